// Round 1
// baseline (60.883 us; speedup 1.0000x reference)
//
#include <hip/hip_runtime.h>

using short8 = __attribute__((ext_vector_type(8))) short;
using f32x4  = __attribute__((ext_vector_type(4))) float;
using u32x4  = __attribute__((ext_vector_type(4))) unsigned int;

#define NB 8
#define NC 256
#define NH 48
#define NW 64
#define H2 24
#define W2 32
#define ND 21
#define HW (NH * NW)        /* 3072 */
#define CSTRIDE HW          /* per-channel stride in floats */

__device__ __forceinline__ unsigned int f2bf(float f) {
    unsigned int u = __builtin_bit_cast(unsigned int, f);
    return (u + 0x7fffu + ((u >> 16) & 1u)) >> 16;   // RNE truncate to bf16
}

// byte offset into a [64 rows][256 ch] bf16 LDS tile, XOR-swizzled so that
// lanes reading different rows at the same channel-range spread across banks
__device__ __forceinline__ unsigned int swz_off(int row, int cb) {
    return (row << 9) + (((cb) << 1) ^ (((row >> 1) & 7) << 4));
}

// stage one full-resolution row (64 x, 256 c) of f32 global data into LDS bf16,
// transposed to [x][c] layout. 512 threads.
__device__ __forceinline__ void stage_row(unsigned short* lds, const float* src, int tid) {
    int xp = tid & 31;          // x pair: x = 2*xp, 2*xp+1
    int cg = tid >> 5;          // 0..15, 8 channels each
    const float* s = src + 2 * xp;
    #pragma unroll
    for (int cc = 0; cc < 2; ++cc) {
        int c0 = cc * 128 + cg * 8;
        u32x4 p0, p1;
        #pragma unroll
        for (int e = 0; e < 4; ++e) {
            float2 va = *reinterpret_cast<const float2*>(s + (size_t)(c0 + 2 * e    ) * CSTRIDE);
            float2 vb = *reinterpret_cast<const float2*>(s + (size_t)(c0 + 2 * e + 1) * CSTRIDE);
            p0[e] = f2bf(va.x) | (f2bf(vb.x) << 16);
            p1[e] = f2bf(va.y) | (f2bf(vb.y) << 16);
        }
        *reinterpret_cast<u32x4*>(reinterpret_cast<char*>(lds) + swz_off(2 * xp,     c0)) = p0;
        *reinterpret_cast<u32x4*>(reinterpret_cast<char*>(lds) + swz_off(2 * xp + 1, c0)) = p1;
    }
}

__device__ __forceinline__ short8 frag_load(const unsigned short* lds, int row, int cb) {
    return *reinterpret_cast<const short8*>(reinterpret_cast<const char*>(lds) + swz_off(row, cb));
}

__global__ __launch_bounds__(512, 4) void corr_kernel(const float* __restrict__ f1,
                                                      const float* __restrict__ f2,
                                                      float* __restrict__ out) {
    __shared__ __align__(16) unsigned short Alds[64 * 256];   // f1 row, bf16 [x][c]
    __shared__ __align__(16) unsigned short Blds[64 * 256];   // f2 row, bf16 [x][c]
    __shared__ float Slds[64][33];                            // S scores [x=2*ux+px][vx]

    int bid = blockIdx.x;
    // bijective XCD swizzle: 384 = 8 XCD * 48; keeps one (b,py) group's uy-blocks on one XCD
    int swz = (bid & 7) * 48 + (bid >> 3);
    int uy = swz % 24;
    int g  = swz / 24;            // b*2 + py
    int py = g & 1;
    int b  = g >> 1;
    int y  = 2 * uy + py;

    int tid  = threadIdx.x;
    int lane = tid & 63;
    int w    = tid >> 6;

    const float* f1row = f1 + (size_t)b * NC * HW + (size_t)y * NW;
    const float* f2base = f2 + (size_t)b * NC * HW;
    float* outb = out + (size_t)b * 441 * HW + (size_t)y * NW;   // + d*HW + x

    // zero-fill output rows whose displaced source row is out of bounds
    for (int i = 0; i < ND; ++i) {
        int vy = uy + i - 10;
        if (vy >= 0 && vy < H2) continue;
        for (int t = tid; t < ND * 64; t += 512) {
            int j = t >> 6, x = t & 63;
            outb[(size_t)(i * ND + j) * HW + x] = 0.f;
        }
    }

    // stage A (f1 row) once
    stage_row(Alds, f1row, tid);
    __syncthreads();

    // wave tile assignment: 8 waves = {px} x {M-tile} x {N-tile}
    int px = w & 1;
    int m0 = ((w >> 1) & 1) * 16;
    int n0 = ((w >> 2) & 1) * 16;
    int l15 = lane & 15;
    int kgr = (lane >> 4) * 8;

    // hoist A fragments (reused across all 21 vy steps)
    short8 afrag[8];
    int arow = 2 * (m0 + l15) + px;
    #pragma unroll
    for (int kk = 0; kk < 8; ++kk) afrag[kk] = frag_load(Alds, arow, kk * 32 + kgr);

    int brow = 2 * (n0 + l15) + px;
    int srow = 2 * (m0 + (lane >> 4) * 4) + px;   // + 2*r
    int scol = n0 + l15;

    for (int vy = uy - 10; vy <= uy + 10; ++vy) {
        if (vy < 0 || vy >= H2) continue;          // uniform per WG
        int i  = vy - uy + 10;
        int y2 = 2 * vy + py;

        __syncthreads();   // prev MFMA B-reads + prev gather S-reads done
        stage_row(Blds, f2base + (size_t)y2 * NW, tid);
        __syncthreads();   // B ready

        f32x4 acc = {0.f, 0.f, 0.f, 0.f};
        #pragma unroll
        for (int kk = 0; kk < 8; ++kk) {
            short8 bfrag = frag_load(Blds, brow, kk * 32 + kgr);
            acc = __builtin_amdgcn_mfma_f32_16x16x32_bf16(afrag[kk], bfrag, acc, 0, 0, 0);
        }

        // C/D layout: col = lane&15 (-> vx), row = (lane>>4)*4 + r (-> ux)
        #pragma unroll
        for (int r = 0; r < 4; ++r)
            Slds[srow + 2 * r][scol] = acc[r] * (1.f / 256.f);
        __syncthreads();   // S ready

        // banded gather: out[ux, j] = S[ux, ux + j - 10]; coalesced 256B stores
        for (int t = tid; t < ND * 64; t += 512) {
            int j = t >> 6, x = t & 63;
            int vx = (x >> 1) + j - 10;
            float v = ((unsigned)vx < 32u) ? Slds[x][vx] : 0.f;
            outb[(size_t)(i * ND + j) * HW + x] = v;
        }
    }
}

extern "C" void kernel_launch(void* const* d_in, const int* in_sizes, int n_in,
                              void* d_out, int out_size, void* d_ws, size_t ws_size,
                              hipStream_t stream) {
    const float* in1 = (const float*)d_in[0];
    const float* in2 = (const float*)d_in[1];
    float* o = (float*)d_out;
    hipLaunchKernelGGL(corr_kernel, dim3(384), dim3(512), 0, stream, in1, in2, o);
}